// Round 2
// baseline (1028.044 us; speedup 1.0000x reference)
//
#include <hip/hip_runtime.h>
#include <stdint.h>

// TwoMaxLayerPoolingAggregator: masked neighbor max-pool + [N,128]@[128,128] GEMM
// + concat(self, from_neighs) + relu.  N=50000, K=32, D=128.
// All float tensors are FP32 (R1 post-mortem: reading them as bf16 pairs gave
// inf from mantissa garbage), adj_mask int32, output fp32.
// HBM-bound on neigh_vecs (819 MB dense): skip loads for masked-out neighbors
// (~50%) via a wave-uniform ballot bitmask; each neighbor row is a contiguous
// 512 B so skipping keeps full coalescing.

#define D_DIM 128
#define K_DIM 32
#define NPB   64      // nodes per block
#define HPAD  132     // padded LDS row stride in floats (132%32==4 -> conflict-free b128)

__global__ __launch_bounds__(256, 4) void agg_kernel(
    const float* __restrict__ self_vecs,   // [N,128] f32
    const float* __restrict__ neigh_vecs,  // [N,32,128] f32
    const int*   __restrict__ adj_mask,    // [N,32] i32
    const float* __restrict__ W,           // [128,128] f32
    float*       __restrict__ out,         // [N,256] f32
    int N)
{
    __shared__ float hlds[NPB * HPAD];

    const int t    = threadIdx.x;
    const int wave = t >> 6;
    const int lane = t & 63;
    const int base = blockIdx.x * NPB;

    // ---------------- Phase 1: masked max-pool (wave handles 16 nodes) -----
    // lane owns feature pair d = {2*lane, 2*lane+1} via float2 (512 B/row/wave)
    #pragma unroll 1
    for (int m = 0; m < 16; ++m) {
        const int lm = wave * 16 + m;
        const int n  = base + lm;
        if (n < N) {
            int mv = (lane < K_DIM) ? adj_mask[(size_t)n * K_DIM + lane] : 0;
            unsigned long long bits = __ballot(mv > 0);  // wave-uniform valid-k set
            const float2* row = (const float2*)(neigh_vecs + (size_t)n * (K_DIM * D_DIM));
            float h0 = -1e10f, h1 = -1e10f;
            while (bits) {
                unsigned long long b2 = bits & (bits - 1ull);
                int k0 = __builtin_ctzll(bits);
                int k1 = b2 ? __builtin_ctzll(b2) : k0;  // dup load if odd count (L1-hot)
                bits = b2 & (b2 - 1ull);
                float2 v0 = row[k0 * 64 + lane];         // 2 independent loads -> MLP
                float2 v1 = row[k1 * 64 + lane];
                h0 = fmaxf(h0, fmaxf(v0.x, v1.x));
                h1 = fmaxf(h1, fmaxf(v0.y, v1.y));
            }
            *(float2*)&hlds[lm * HPAD + 2 * lane] = make_float2(h0, h1);

            // self half of the output: relu, fp32 passthrough
            float2 sv = ((const float2*)self_vecs)[(size_t)n * 64 + lane];
            ((float2*)out)[(size_t)n * 128 + lane] =
                make_float2(fmaxf(sv.x, 0.f), fmaxf(sv.y, 0.f));
        }
    }
    __syncthreads();

    // ---------------- Phase 2: from_neighs = h @ W, relu, store ------------
    // thread = (mt, jt): 4 nodes {mt,mt+16,mt+32,mt+48} x 8 cols [8*jt..8*jt+7]
    const int jt = t & 15;
    const int mt = t >> 4;
    float acc[4][8];
    #pragma unroll
    for (int q = 0; q < 4; ++q)
        #pragma unroll
        for (int j = 0; j < 8; ++j) acc[q][j] = 0.f;

    const float4* Wv = (const float4*)W;   // 32 float4 per 128-f32 row
    for (int d = 0; d < D_DIM; d += 4) {
        float4 hq[4];
        #pragma unroll
        for (int q = 0; q < 4; ++q)
            hq[q] = *(const float4*)&hlds[(mt + 16 * q) * HPAD + d];
        #pragma unroll
        for (int dd = 0; dd < 4; ++dd) {
            float4 wa = Wv[(size_t)(d + dd) * 32 + 2 * jt];     // W[d+dd][8jt..8jt+3]
            float4 wb = Wv[(size_t)(d + dd) * 32 + 2 * jt + 1]; // W[d+dd][8jt+4..8jt+7]
            float w[8] = { wa.x, wa.y, wa.z, wa.w, wb.x, wb.y, wb.z, wb.w };
            #pragma unroll
            for (int q = 0; q < 4; ++q) {
                float hv = (&hq[q].x)[dd];
                #pragma unroll
                for (int j = 0; j < 8; ++j)
                    acc[q][j] = fmaf(hv, w[j], acc[q][j]);
            }
        }
    }

    #pragma unroll
    for (int q = 0; q < 4; ++q) {
        int n = base + mt + 16 * q;
        if (n < N) {
            float* op = out + (size_t)n * 256 + 128 + 8 * jt;
            *(float4*)(op)     = make_float4(fmaxf(acc[q][0], 0.f), fmaxf(acc[q][1], 0.f),
                                             fmaxf(acc[q][2], 0.f), fmaxf(acc[q][3], 0.f));
            *(float4*)(op + 4) = make_float4(fmaxf(acc[q][4], 0.f), fmaxf(acc[q][5], 0.f),
                                             fmaxf(acc[q][6], 0.f), fmaxf(acc[q][7], 0.f));
        }
    }
}

extern "C" void kernel_launch(void* const* d_in, const int* in_sizes, int n_in,
                              void* d_out, int out_size, void* d_ws, size_t ws_size,
                              hipStream_t stream) {
    const float* self_vecs = (const float*)d_in[0];
    const float* neigh     = (const float*)d_in[1];
    const int*   mask      = (const int*)d_in[2];
    const float* W         = (const float*)d_in[3];
    float* out = (float*)d_out;

    int N = in_sizes[0] / D_DIM;            // 50000
    int grid = (N + NPB - 1) / NPB;         // 782 blocks
    agg_kernel<<<grid, 256, 0, stream>>>(self_vecs, neigh, mask, W, out, N);
}